// Round 4
// baseline (1362.584 us; speedup 1.0000x reference)
//
#include <hip/hip_runtime.h>

typedef unsigned short u16;
typedef unsigned int u32;
using bf8 = __attribute__((ext_vector_type(8))) short;  // 8 bf16 (4 VGPRs)
using f4  = __attribute__((ext_vector_type(4))) float;  // MFMA acc

#define DEV __device__ __forceinline__

// B=2, S=2048, HID=4096, H=32, KV=8, D=128, G=4
// q scale folded into rope: (1/sqrt(128)) * log2(e)  -> softmax in exp2 domain
#define QSCALE (0.08838834764831845f * 1.4426950408889634f)

DEV u16 f2b(float f) {            // RNE fp32 -> bf16 bits
  u32 u = __float_as_uint(f);
  u32 r = u + 0x7fff + ((u >> 16) & 1);
  return (u16)(r >> 16);
}
DEV u32 f2b_u(u32 u) {            // RNE from fp32 bits
  return (u + 0x7fff + ((u >> 16) & 1)) >> 16;
}
DEV float b2f(u32 bits) { return __uint_as_float(bits << 16); }

#define GLOAD16(g, l)                                                          \
  __builtin_amdgcn_global_load_lds((__attribute__((address_space(1))) u32*)(g),\
                                   (__attribute__((address_space(3))) u32*)(l),\
                                   16, 0, 0)

DEV f4 mfma16(bf8 a, bf8 b, f4 c) {
  return __builtin_amdgcn_mfma_f32_16x16x32_bf16(a, b, c, 0, 0, 0);
}

// DPP row_ror reduction over 16-lane rows (VALU pipe, not LDS pipe).
#define ROR_F(x, n)                                                            \
  __int_as_float(__builtin_amdgcn_update_dpp(                                  \
      0, __float_as_int(x), 0x120 + (n), 0xf, 0xf, true))
DEV float rowmax16(float x) {
  x = fmaxf(x, ROR_F(x, 1));
  x = fmaxf(x, ROR_F(x, 2));
  x = fmaxf(x, ROR_F(x, 4));
  x = fmaxf(x, ROR_F(x, 8));
  return x;
}
DEV float rowsum16(float x) {
  x += ROR_F(x, 1);
  x += ROR_F(x, 2);
  x += ROR_F(x, 4);
  x += ROR_F(x, 8);
  return x;
}

// =====================================================================
// Input normalizer: copies src -> dst as bf16. Detects src dtype at
// runtime from probe[0] (cos[0]==1.0: fp32 -> 0x3F800000, bf16 -> 0x3F803F80).
// n8 = element count / 8.
// =====================================================================
__global__ __launch_bounds__(256) void convert_kernel(
    const u16* __restrict__ src, u16* __restrict__ dst,
    const u32* __restrict__ probe, int n8) {
  const int t = blockIdx.x * 256 + threadIdx.x;
  if (t >= n8) return;
  const bool isf32 = (probe[0] == 0x3F800000u);
  const uint4* s4 = (const uint4*)src;
  uint4* d4 = (uint4*)dst;
  if (!isf32) {
    d4[t] = s4[t];
    return;
  }
  uint4 a = s4[2 * t];
  uint4 b = s4[2 * t + 1];
  uint4 o;
  o.x = f2b_u(a.x) | (f2b_u(a.y) << 16);
  o.y = f2b_u(a.z) | (f2b_u(a.w) << 16);
  o.z = f2b_u(b.x) | (f2b_u(b.y) << 16);
  o.w = f2b_u(b.z) | (f2b_u(b.w) << 16);
  d4[t] = o;
}

// =====================================================================
// GEMM core: C[128x128 tile] = A(M x K, rm) * W(N x K, rm)^T  (m97 pattern)
// =====================================================================
DEV void gemm_core(const u16* __restrict__ A, const u16* __restrict__ W,
                   int lda, int ldw, int K, int mb, int nb,
                   u16* As, u16* Bs, f4 (&acc)[4][4]) {
  const int tid = threadIdx.x;
  const int lane = tid & 63;
  const int wid = tid >> 6;
  const int l16 = lane & 15;
  const int quad = lane >> 4;
  const int wm = (wid >> 1) * 64;
  const int wn = (wid & 1) * 64;

  const int c0 = wid * 2;
  const int rowA0 = c0 * 16 + (lane >> 2);
  const int colb = (lane & 3) * 16;

  const char* gA = (const char*)(A + (size_t)(mb * 128 + rowA0) * lda) + colb;
  const char* gB = (const char*)(W + (size_t)(nb * 128 + rowA0) * ldw) + colb;
  char* lA = (char*)As + c0 * 1024;
  char* lB = (char*)Bs + c0 * 1024;
  const size_t strideA = (size_t)lda * 32;
  const size_t strideB = (size_t)ldw * 32;

  for (int k0 = 0; k0 < K; k0 += 32) {
    __syncthreads();
    GLOAD16(gA + (size_t)k0 * 2, lA);
    GLOAD16(gA + (size_t)k0 * 2 + strideA, lA + 1024);
    GLOAD16(gB + (size_t)k0 * 2, lB);
    GLOAD16(gB + (size_t)k0 * 2 + strideB, lB + 1024);
    __syncthreads();

    bf8 af[4], bw[4];
#pragma unroll
    for (int t = 0; t < 4; t++) {
      af[t] = *(const bf8*)(As + (wm + t * 16 + l16) * 32 + quad * 8);
      bw[t] = *(const bf8*)(Bs + (wn + t * 16 + l16) * 32 + quad * 8);
    }
#pragma unroll
    for (int mt = 0; mt < 4; mt++)
#pragma unroll
      for (int nt = 0; nt < 4; nt++)
        acc[mt][nt] = mfma16(af[mt], bw[nt], acc[mt][nt]);
  }
}

// =====================================================================
// Fused QKV projection. grid (32, 48): y<32 -> Q, y<40 -> K, else V.
// V written transposed: vt[(b*KV+kv)*D + d][s].
// =====================================================================
__global__ __launch_bounds__(256) void gemm_qkv_kernel(
    const u16* __restrict__ hidden, const u16* __restrict__ wq,
    const u16* __restrict__ wk, const u16* __restrict__ wv,
    u16* __restrict__ qo, u16* __restrict__ ko, u16* __restrict__ vto) {
  __shared__ u16 As[128 * 32];
  __shared__ u16 Bs[128 * 32];
  const int mb = blockIdx.x, yb = blockIdx.y;
  const u16* W;
  u16* C;
  int nb, ldc, mode;
  if (yb < 32)      { W = wq; C = qo;  nb = yb;      ldc = 4096; mode = 0; }
  else if (yb < 40) { W = wk; C = ko;  nb = yb - 32; ldc = 1024; mode = 0; }
  else              { W = wv; C = vto; nb = yb - 40; ldc = 0;    mode = 1; }

  f4 acc[4][4];
#pragma unroll
  for (int i = 0; i < 4; i++)
#pragma unroll
    for (int j = 0; j < 4; j++) acc[i][j] = (f4){0.f, 0.f, 0.f, 0.f};

  gemm_core(hidden, W, 4096, 4096, 4096, mb, nb, As, Bs, acc);

  const int tid = threadIdx.x, lane = tid & 63, wid = tid >> 6;
  const int l16 = lane & 15, quad = lane >> 4;
  const int wm = (wid >> 1) * 64, wn = (wid & 1) * 64;

  if (mode == 0) {
#pragma unroll
    for (int mt = 0; mt < 4; mt++)
#pragma unroll
      for (int nt = 0; nt < 4; nt++) {
        const int n = nb * 128 + wn + nt * 16 + l16;
        const int m0 = mb * 128 + wm + mt * 16 + quad * 4;
#pragma unroll
        for (int r = 0; r < 4; r++)
          C[(size_t)(m0 + r) * ldc + n] = f2b(acc[mt][nt][r]);
      }
  } else {
    // C rows are consecutive s at fixed d=n -> contiguous in vt[d][s]
#pragma unroll
    for (int mt = 0; mt < 4; mt++)
#pragma unroll
      for (int nt = 0; nt < 4; nt++) {
        const int n = nb * 128 + wn + nt * 16 + l16;
        const int m0 = mb * 128 + wm + mt * 16 + quad * 4;
        const int b_ = m0 >> 11, s0 = m0 & 2047;
        ushort4 pk;
        pk.x = f2b(acc[mt][nt][0]);
        pk.y = f2b(acc[mt][nt][1]);
        pk.z = f2b(acc[mt][nt][2]);
        pk.w = f2b(acc[mt][nt][3]);
        *(ushort4*)(vto + ((size_t)(b_ * 1024 + n) << 11) + s0) = pk;
      }
  }
}

// =====================================================================
// O projection: out(FP32) = attn(B*S x 4096, bf16) @ wo(4096 x 4096)^T.
// =====================================================================
__global__ __launch_bounds__(256) void gemm_o_kernel(
    const u16* __restrict__ A, const u16* __restrict__ W,
    float* __restrict__ C) {
  __shared__ u16 As[128 * 32];
  __shared__ u16 Bs[128 * 32];
  const int mb = blockIdx.x, nb = blockIdx.y;
  f4 acc[4][4];
#pragma unroll
  for (int i = 0; i < 4; i++)
#pragma unroll
    for (int j = 0; j < 4; j++) acc[i][j] = (f4){0.f, 0.f, 0.f, 0.f};

  gemm_core(A, W, 4096, 4096, 4096, mb, nb, As, Bs, acc);

  const int tid = threadIdx.x, lane = tid & 63, wid = tid >> 6;
  const int l16 = lane & 15, quad = lane >> 4;
  const int wm = (wid >> 1) * 64, wn = (wid & 1) * 64;
#pragma unroll
  for (int mt = 0; mt < 4; mt++)
#pragma unroll
    for (int nt = 0; nt < 4; nt++) {
      const int n = nb * 128 + wn + nt * 16 + l16;
      const int m0 = mb * 128 + wm + mt * 16 + quad * 4;
#pragma unroll
      for (int r = 0; r < 4; r++)
        C[(size_t)(m0 + r) * 4096 + n] = acc[mt][nt][r];
    }
}

// =====================================================================
// RoPE in-place on bf16 (B,S,nh,128). thread = 8 elems (4 even/odd pairs).
// =====================================================================
__global__ void rope_kernel(u16* __restrict__ x, const u16* __restrict__ cs,
                            const u16* __restrict__ sn, int shift, float scale,
                            int nthreads) {
  const int t = blockIdx.x * 256 + threadIdx.x;
  if (t >= nthreads) return;
  const size_t e = (size_t)t * 8;
  const int d = (int)(e & 127);
  const int s = (int)((e >> shift) & 2047);
  uint4 xv = *(const uint4*)(x + e);
  uint4 cv = *(const uint4*)(cs + (size_t)s * 128 + d);
  uint4 sv = *(const uint4*)(sn + (size_t)s * 128 + d);
  u32 xw[4] = {xv.x, xv.y, xv.z, xv.w};
  u32 cw[4] = {cv.x, cv.y, cv.z, cv.w};
  u32 sw[4] = {sv.x, sv.y, sv.z, sv.w};
  u32 ow[4];
#pragma unroll
  for (int i = 0; i < 4; i++) {
    float x0 = b2f(xw[i] & 0xffff), x1 = b2f(xw[i] >> 16);
    float c = b2f(cw[i] & 0xffff);   // cos[s,2i] == cos[s,2i+1]
    float si = b2f(sw[i] & 0xffff);
    float o0 = (x0 * c - x1 * si) * scale;
    float o1 = (x1 * c + x0 * si) * scale;
    ow[i] = (u32)f2b(o0) | ((u32)f2b(o1) << 16);
  }
  uint4 ov = {ow[0], ow[1], ow[2], ow[3]};
  *(uint4*)(x + e) = ov;
}

// =====================================================================
// Flash attention v2 (causal, GQA). Block = one (b, kv) group x 64 queries:
// 4 waves, wave = one full head (h = kv*4 + wid), 64 q x 128 d accumulator
// per wave. K/V staged ONCE per GQA group (4x less staging than v1).
// Online softmax in exp2 domain; reductions via DPP row_ror (VALU pipe).
// Scores processed per 16-row m-tile to cap register pressure.
// 2 barriers per K-tile (P is wave-private).
// =====================================================================
__global__ __launch_bounds__(256, 2) void attn_kernel(
    const u16* __restrict__ q, const u16* __restrict__ k,
    const u16* __restrict__ vt, u16* __restrict__ attn) {
  __shared__ u16 Ks[64 * 136];     // [key][d], ld 136
  __shared__ u16 Vt[128 * 72];     // [d][key], ld 72
  __shared__ u16 Ps[4][64 * 72];   // per-wave P [q][key], ld 72

  const int bx = blockIdx.x;
  // pair long+short causal blocks so co-resident pairs have ~equal work
  const int qblk = (bx & 1) ? (31 - (bx >> 1)) : (bx >> 1);
  const int kv = blockIdx.y, b = blockIdx.z;
  const int tid = threadIdx.x, lane = tid & 63, wid = tid >> 6;
  const int l16 = lane & 15, quad = lane >> 4;
  const int h = kv * 4 + wid;  // wave's head

  // register-resident Q A-frags: aq[mt][ks] rows qblk*64+mt*16+l16
  bf8 aq[4][4];
  const u16* qbase = q + ((size_t)(b * 2048 + qblk * 64) * 32 + h) * 128;
#pragma unroll
  for (int mt = 0; mt < 4; mt++) {
    const u16* qp = qbase + (size_t)(mt * 16 + l16) * 4096;
#pragma unroll
    for (int ks = 0; ks < 4; ks++)
      aq[mt][ks] = *(const bf8*)(qp + ks * 32 + quad * 8);
  }

  f4 accO[4][8];  // [mt][nd]
#pragma unroll
  for (int i = 0; i < 4; i++)
#pragma unroll
    for (int j = 0; j < 8; j++) accO[i][j] = (f4){0.f, 0.f, 0.f, 0.f};
  float mrow[4][4], lrow[4][4];  // [mt][r]
#pragma unroll
  for (int i = 0; i < 4; i++)
#pragma unroll
    for (int r = 0; r < 4; r++) {
      mrow[i][r] = -1e30f;
      lrow[i][r] = 0.f;
    }

  const u16* kp = k + ((size_t)(b * 2048) * 8 + kv) * 128;  // key stride 1024
  const u16* vp = vt + (size_t)(b * 8 + kv) * 128 * 2048;   // d stride 2048
  u16* Pw = Ps[wid];

  for (int kt = 0; kt <= qblk; kt++) {
    const int key0 = kt * 64;
    __syncthreads();  // PV of previous iter done reading Ks/Vt
    // stage K tile [64][128]: 4 reps x 256 threads x 8 u16
#pragma unroll
    for (int rep = 0; rep < 4; rep++) {
      const int e = rep * 2048 + tid * 8;
      const int row = e >> 7, col = e & 127;
      *(uint4*)(Ks + row * 136 + col) =
          *(const uint4*)(kp + (size_t)(key0 + row) * 1024 + col);
    }
    // stage Vt tile [128][64]
#pragma unroll
    for (int rep = 0; rep < 4; rep++) {
      const int e = rep * 2048 + tid * 8;
      const int row = e >> 6, col = e & 63;
      *(uint4*)(Vt + row * 72 + col) =
          *(const uint4*)(vp + (size_t)row * 2048 + key0 + col);
    }
    __syncthreads();

    const bool diag = (kt == qblk);

    // ---- scores + softmax, one 16-row m-tile at a time ----
#pragma unroll
    for (int mt = 0; mt < 4; mt++) {
      f4 sc[4];
#pragma unroll
      for (int nt = 0; nt < 4; nt++) sc[nt] = (f4){0.f, 0.f, 0.f, 0.f};
#pragma unroll
      for (int ks = 0; ks < 4; ks++)
#pragma unroll
        for (int nt = 0; nt < 4; nt++) {
          bf8 bk = *(const bf8*)(Ks + (nt * 16 + l16) * 136 + ks * 32 +
                                 quad * 8);
          sc[nt] = mfma16(aq[mt][ks], bk, sc[nt]);
        }

      const int qrow = mt * 16 + quad * 4;  // local q row base of this lane
#pragma unroll
      for (int r = 0; r < 4; r++) {
        if (diag) {
#pragma unroll
          for (int nt = 0; nt < 4; nt++)
            if (nt * 16 + l16 > qrow + r) sc[nt][r] = -1e30f;
        }
        float mx = fmaxf(fmaxf(sc[0][r], sc[1][r]), fmaxf(sc[2][r], sc[3][r]));
        mx = rowmax16(mx);
        const float mn = fmaxf(mrow[mt][r], mx);
        const float alpha = exp2f(mrow[mt][r] - mn);
        mrow[mt][r] = mn;
        float p0 = exp2f(sc[0][r] - mn);
        float p1 = exp2f(sc[1][r] - mn);
        float p2 = exp2f(sc[2][r] - mn);
        float p3 = exp2f(sc[3][r] - mn);
        float ps = rowsum16((p0 + p1) + (p2 + p3));
        lrow[mt][r] = lrow[mt][r] * alpha + ps;
#pragma unroll
        for (int nd = 0; nd < 8; nd++) accO[mt][nd][r] *= alpha;
        Pw[(qrow + r) * 72 + 0 * 16 + l16] = f2b(p0);
        Pw[(qrow + r) * 72 + 1 * 16 + l16] = f2b(p1);
        Pw[(qrow + r) * 72 + 2 * 16 + l16] = f2b(p2);
        Pw[(qrow + r) * 72 + 3 * 16 + l16] = f2b(p3);
      }
    }

    // ---- PV: accO[64q x 128d] += P[64x64] * V[64x128] (wave-private P) ----
#pragma unroll
    for (int ks2 = 0; ks2 < 2; ks2++) {
      bf8 ap[4];
#pragma unroll
      for (int mt = 0; mt < 4; mt++)
        ap[mt] = *(const bf8*)(Pw + (mt * 16 + l16) * 72 + ks2 * 32 + quad * 8);
#pragma unroll
      for (int nd = 0; nd < 8; nd++) {
        bf8 bv = *(const bf8*)(Vt + (nd * 16 + l16) * 72 + ks2 * 32 + quad * 8);
#pragma unroll
        for (int mt = 0; mt < 4; mt++)
          accO[mt][nd] = mfma16(ap[mt], bv, accO[mt][nd]);
      }
    }
  }

  // ---- epilogue: attn[b][s][h][d] bf16 ----
#pragma unroll
  for (int mt = 0; mt < 4; mt++) {
    float inv[4];
#pragma unroll
    for (int r = 0; r < 4; r++) inv[r] = 1.0f / lrow[mt][r];
#pragma unroll
    for (int nd = 0; nd < 8; nd++)
#pragma unroll
      for (int r = 0; r < 4; r++) {
        const int s = qblk * 64 + mt * 16 + quad * 4 + r;
        const int dcol = nd * 16 + l16;
        attn[((size_t)(b * 2048 + s) * 32 + h) * 128 + dcol] =
            f2b(accO[mt][nd][r] * inv[r]);
      }
  }
}

// =====================================================================
extern "C" void kernel_launch(void* const* d_in, const int* in_sizes, int n_in,
                              void* d_out, int out_size, void* d_ws,
                              size_t ws_size, hipStream_t stream) {
  const u16* hidden = (const u16*)d_in[0];
  const u16* cosp = (const u16*)d_in[1];
  const u16* sinp = (const u16*)d_in[2];
  const u16* wq = (const u16*)d_in[3];
  const u16* wk = (const u16*)d_in[4];
  const u16* wv = (const u16*)d_in[5];
  const u16* wo = (const u16*)d_in[6];
  const u32* probe = (const u32*)d_in[1];  // cos[0] == 1.0
  float* out = (float*)d_out;              // fp32 output

  char* ws = (char*)d_ws;
  // hidden_n region is reused as attnb after gemm_qkv completes.
  u16* hidden_n = (u16*)(ws);                    // 32 MiB
  u16* attnb    = (u16*)(ws);                    // 32 MiB (alias, later)
  u16* qb       = (u16*)(ws + 33554432);         // 32 MiB
  u16* kb       = (u16*)(ws + 67108864);         //  8 MiB
  u16* vtb      = (u16*)(ws + 75497472);         //  8 MiB
  u16* wq_n     = (u16*)(ws + 83886080);         // 32 MiB
  u16* wk_n     = (u16*)(ws + 117440512);        //  8 MiB
  u16* wv_n     = (u16*)(ws + 125829120);        //  8 MiB
  u16* wo_n     = (u16*)(ws + 134217728);        // 32 MiB
  u16* cos_n    = (u16*)(ws + 167772160);        // 0.5 MiB
  u16* sin_n    = (u16*)(ws + 168296448);        // 0.5 MiB

  dim3 blk(256);
  // normalize all inputs to bf16 (runtime dtype detection via probe)
  convert_kernel<<<dim3(8192), blk, 0, stream>>>(hidden, hidden_n, probe,
                                                 2097152);
  convert_kernel<<<dim3(8192), blk, 0, stream>>>(wq, wq_n, probe, 2097152);
  convert_kernel<<<dim3(2048), blk, 0, stream>>>(wk, wk_n, probe, 524288);
  convert_kernel<<<dim3(2048), blk, 0, stream>>>(wv, wv_n, probe, 524288);
  convert_kernel<<<dim3(8192), blk, 0, stream>>>(wo, wo_n, probe, 2097152);
  convert_kernel<<<dim3(128), blk, 0, stream>>>(cosp, cos_n, probe, 32768);
  convert_kernel<<<dim3(128), blk, 0, stream>>>(sinp, sin_n, probe, 32768);

  gemm_qkv_kernel<<<dim3(32, 48), blk, 0, stream>>>(hidden_n, wq_n, wk_n, wv_n,
                                                    qb, kb, vtb);
  rope_kernel<<<dim3(8192), blk, 0, stream>>>(qb, cos_n, sin_n, 12, QSCALE,
                                              2097152);
  rope_kernel<<<dim3(2048), blk, 0, stream>>>(kb, cos_n, sin_n, 10, 1.0f,
                                              524288);
  attn_kernel<<<dim3(32, 8, 2), blk, 0, stream>>>(qb, kb, vtb, attnb);
  gemm_o_kernel<<<dim3(32, 32), blk, 0, stream>>>(attnb, wo_n, out);
}